// Round 3
// baseline (1864.406 us; speedup 1.0000x reference)
//
#include <hip/hip_runtime.h>
#include <hip/hip_bf16.h>

#define LNUM 6
#define BB 16
#define TT 512
#define DD 512
#define HH 8
#define AA 64
#define FFD 2048
#define EE 200000
#define BIASDIM 4
#define ATT_NEG (-3.402823466e38f)

typedef __bf16 bf16_t;
typedef __attribute__((ext_vector_type(8))) __bf16 bf16x8;
typedef __attribute__((ext_vector_type(4))) float f32x4;

typedef __attribute__((address_space(3))) void lds_void;
typedef const __attribute__((address_space(1))) void glb_void;

__device__ __forceinline__ void async_load16(const bf16_t* g, bf16_t* l) {
    __builtin_amdgcn_global_load_lds((glb_void*)g, (lds_void*)l, 16, 0, 0);
}

// ---------------------------------------------------------------------------
// Embedding + positional encoding (fp32 out)
// ---------------------------------------------------------------------------
__global__ __launch_bounds__(256) void embed_pe_kernel(
    const int* __restrict__ tokens, const float* __restrict__ embed,
    float* __restrict__ x)
{
    int idx = blockIdx.x * 256 + threadIdx.x;
    int d  = idx & (DD - 1);
    int bt = idx >> 9;
    int t  = bt & (TT - 1);
    int tok = tokens[bt];
    float e = embed[(long long)tok * DD + d] * 22.62741699796952f; // sqrt(512)
    float p = (float)(2 * (d >> 1)) * (1.0f / (float)DD);
    float denom = exp2f(p * 13.287712379549449f);  // 10000^p
    float angle = (float)t / denom;
    float pe = (d & 1) ? cosf(angle) : sinf(angle);
    x[idx] = e + pe;
}

// ---------------------------------------------------------------------------
// LayerNorm over D=512, fp32 in, TO out
// ---------------------------------------------------------------------------
template <typename TO>
__global__ __launch_bounds__(256) void ln_kernel(
    const float* __restrict__ x, TO* __restrict__ y,
    const float* __restrict__ g, const float* __restrict__ b)
{
    long long row = blockIdx.x;
    const float* xr = x + row * DD;
    int tid = threadIdx.x;
    float v0 = xr[tid], v1 = xr[tid + 256];
    float s = v0 + v1, sq = v0 * v0 + v1 * v1;
#pragma unroll
    for (int o = 32; o > 0; o >>= 1) {
        s  += __shfl_down(s, o);
        sq += __shfl_down(sq, o);
    }
    __shared__ float ss[4], sq4[4];
    if ((tid & 63) == 0) { ss[tid >> 6] = s; sq4[tid >> 6] = sq; }
    __syncthreads();
    float st  = ss[0] + ss[1] + ss[2] + ss[3];
    float sqt = sq4[0] + sq4[1] + sq4[2] + sq4[3];
    float mean = st * (1.0f / DD);
    float var  = sqt * (1.0f / DD) - mean * mean;
    float inv  = rsqrtf(var + 1e-3f);
    y[row * DD + tid]       = (TO)((v0 - mean) * inv * g[tid]       + b[tid]);
    y[row * DD + tid + 256] = (TO)((v1 - mean) * inv * g[tid + 256] + b[tid + 256]);
}

// ---------------------------------------------------------------------------
// Fused split-K partial reduce + residual update + LayerNorm.
// v = x + sum_s P[s];  x = v (residual write-back);  y = LN(v)
// ---------------------------------------------------------------------------
template <typename TO, int S>
__global__ __launch_bounds__(256) void reduce_ln_kernel(
    float* __restrict__ x, const float* __restrict__ P,
    TO* __restrict__ y, const float* __restrict__ g, const float* __restrict__ b)
{
    const long long NXc = (long long)BB * TT * DD;
    long long row = blockIdx.x;
    int tid = threadIdx.x;
    long long i0 = row * DD + tid;
    float v0 = x[i0], v1 = x[i0 + 256];
#pragma unroll
    for (int s = 0; s < S; s++) {
        v0 += P[(long long)s * NXc + i0];
        v1 += P[(long long)s * NXc + i0 + 256];
    }
    x[i0] = v0; x[i0 + 256] = v1;
    float s2 = v0 + v1, sq = v0 * v0 + v1 * v1;
#pragma unroll
    for (int o = 32; o > 0; o >>= 1) {
        s2 += __shfl_down(s2, o);
        sq += __shfl_down(sq, o);
    }
    __shared__ float ss[4], sq4[4];
    if ((tid & 63) == 0) { ss[tid >> 6] = s2; sq4[tid >> 6] = sq; }
    __syncthreads();
    float st  = ss[0] + ss[1] + ss[2] + ss[3];
    float sqt = sq4[0] + sq4[1] + sq4[2] + sq4[3];
    float mean = st * (1.0f / DD);
    float var  = sqt * (1.0f / DD) - mean * mean;
    float inv  = rsqrtf(var + 1e-3f);
    y[i0]       = (TO)((v0 - mean) * inv * g[tid]       + b[tid]);
    y[i0 + 256] = (TO)((v1 - mean) * inv * g[tid + 256] + b[tid + 256]);
}

// ---------------------------------------------------------------------------
// ksum[b,t,h] = sum_a k_bf[b,t,h,a]
// ---------------------------------------------------------------------------
__global__ __launch_bounds__(256) void ksum_kernel(
    const bf16_t* __restrict__ k, float* __restrict__ ks)
{
    int idx = blockIdx.x * 256 + threadIdx.x;
    long long base = (long long)idx * AA;
    float s = 0.f;
#pragma unroll
    for (int a = 0; a < AA; a++) s += (float)k[base + a];
    ks[idx] = s;
}

// ---------------------------------------------------------------------------
// Edge-bias scatter (HW fp32 atomic: workspace is coarse-grained)
// ---------------------------------------------------------------------------
__global__ __launch_bounds__(256) void bias_scatter_kernel(
    const int* __restrict__ ab, const float* __restrict__ be,
    const float* __restrict__ bs, float* __restrict__ dense)
{
    __shared__ float ev[BIASDIM];
    int tid = threadIdx.x;
    if (tid < BIASDIM) {
        float s = 0.f;
        for (int a = 0; a < AA; a++) s += be[tid * AA + a] * bs[a];
        ev[tid] = s;
    }
    __syncthreads();
    int e = blockIdx.x * 256 + tid;
    if (e < EE) {
        int ty = ab[e * 4 + 0];
        int b  = ab[e * 4 + 1];
        int q  = ab[e * 4 + 2];
        int kk = ab[e * 4 + 3];
        unsafeAtomicAdd(&dense[((long long)b * TT + q) * TT + kk], ev[ty]);
    }
}

// ---------------------------------------------------------------------------
// Weight convert+transpose: in fp32 [R,Cc] -> out bf16 [Cc,R]. 64x64 tiles.
// ---------------------------------------------------------------------------
__global__ __launch_bounds__(256) void wconv_kernel(
    const float* __restrict__ in, bf16_t* __restrict__ out, int R, int Cc)
{
    __shared__ bf16_t tile[64][65];
    int c0 = blockIdx.x * 64, r0 = blockIdx.y * 64;
    int tid = threadIdx.x;
#pragma unroll
    for (int i = 0; i < 16; i++) {
        int idx = tid + i * 256; int r = idx >> 6, c = idx & 63;
        tile[c][r] = (bf16_t)in[(long long)(r0 + r) * Cc + c0 + c];
    }
    __syncthreads();
#pragma unroll
    for (int i = 0; i < 16; i++) {
        int idx = tid + i * 256; int rr = idx >> 6, cc = idx & 63;
        out[(long long)(c0 + rr) * R + r0 + cc] = tile[rr][cc];
    }
}

struct Ptr4 { const float* p[4]; };

__global__ __launch_bounds__(256) void wconv4_kernel(Ptr4 srcs, bf16_t* __restrict__ out)
{
    __shared__ bf16_t tile[64][65];
    int z = blockIdx.z;
    const float* in = srcs.p[z];
    bf16_t* o = out + (long long)z * DD * DD;
    int c0 = blockIdx.x * 64, r0 = blockIdx.y * 64;
    int tid = threadIdx.x;
#pragma unroll
    for (int i = 0; i < 16; i++) {
        int idx = tid + i * 256; int r = idx >> 6, c = idx & 63;
        tile[c][r] = (bf16_t)in[(long long)(r0 + r) * DD + c0 + c];
    }
    __syncthreads();
#pragma unroll
    for (int i = 0; i < 16; i++) {
        int idx = tid + i * 256; int rr = idx >> 6, cc = idx & 63;
        o[(long long)(c0 + rr) * DD + r0 + cc] = tile[rr][cc];
    }
}

// ---------------------------------------------------------------------------
// v [B,T,H,A] bf16 -> vT [B,H,A,T] bf16
// ---------------------------------------------------------------------------
__global__ __launch_bounds__(256) void vtrans_kernel(
    const bf16_t* __restrict__ v, bf16_t* __restrict__ vT)
{
    __shared__ bf16_t tile[64][65];
    int bh = blockIdx.y; int b = bh >> 3, h = bh & 7;
    int t0 = blockIdx.x * 64;
    int tid = threadIdx.x;
#pragma unroll
    for (int i = 0; i < 16; i++) {
        int idx = tid + i * 256; int r = idx >> 6, c = idx & 63;  // r: t, c: a
        tile[c][r] = v[((long long)(b * TT + t0 + r) * HH + h) * AA + c];
    }
    __syncthreads();
#pragma unroll
    for (int i = 0; i < 16; i++) {
        int idx = tid + i * 256; int a = idx >> 6, t2 = idx & 63;
        vT[(((long long)b * HH + h) * AA + a) * TT + t0 + t2] = tile[a][t2];
    }
}

// ---------------------------------------------------------------------------
// Fused attention. Unchanged.
// ---------------------------------------------------------------------------
__global__ __launch_bounds__(256) void fused_attn_kernel(
    const bf16_t* __restrict__ qg, const bf16_t* __restrict__ kg,
    const bf16_t* __restrict__ vT, const float* __restrict__ dense,
    const float* __restrict__ ksum, const float* __restrict__ masks,
    bf16_t* __restrict__ ctx)
{
    __shared__ __align__(16) bf16_t Ks[64 * 64];
    __shared__ __align__(16) bf16_t Vs[64 * 64];
    __shared__ __align__(16) bf16_t Plds[4 * 16 * 88];

    int tid = threadIdx.x;
    int wave = tid >> 6, lane = tid & 63;
    int row16 = lane & 15, quad = lane >> 4;
    int bh = blockIdx.y; int b = bh >> 3, h = bh & 7;
    int qw = blockIdx.x * 64 + wave * 16;

    bf16x8 qf[2];
    {
        const bf16_t* qp = qg + (((long long)b * TT + qw + row16) * HH + h) * AA + quad * 8;
        qf[0] = *(const bf16x8*)(qp);
        qf[1] = *(const bf16x8*)(qp + 32);
    }

    f32x4 o[4] = {};
    float m_r[4], l_r[4];
#pragma unroll
    for (int r = 0; r < 4; r++) { m_r[r] = -3.0e38f; l_r[r] = 0.f; }

    bf16_t* Pw = Plds + wave * 16 * 88;
    const float* dbase = dense + (long long)b * TT * TT;
    const float* mbase = masks + (long long)b * TT * TT;

    for (int kt = 0; kt < 8; kt++) {
        int t0 = kt * 64;
#pragma unroll
        for (int p = tid; p < 512; p += 256) {
            int r = p >> 3, s = p & 7, c = s ^ (r & 7);
            async_load16(kg + (((long long)b * TT + t0 + r) * HH + h) * AA + c * 8,
                         Ks + p * 8);
        }
#pragma unroll
        for (int p = tid; p < 512; p += 256) {
            int r = p >> 3, s = p & 7, c = s ^ (r & 7);
            async_load16(vT + ((long long)bh * AA + r) * TT + t0 + c * 8,
                         Vs + p * 8);
        }
        __syncthreads();

        f32x4 s4[4] = {};
#pragma unroll
        for (int n = 0; n < 4; n++) {
            int row = n * 16 + row16;
            int sw = row & 7;
            bf16x8 kf0 = *(const bf16x8*)(Ks + row * 64 + ((quad ^ sw) * 8));
            bf16x8 kf1 = *(const bf16x8*)(Ks + row * 64 + (((quad + 4) ^ sw) * 8));
            s4[n] = __builtin_amdgcn_mfma_f32_16x16x32_bf16(qf[0], kf0, s4[n], 0, 0, 0);
            s4[n] = __builtin_amdgcn_mfma_f32_16x16x32_bf16(qf[1], kf1, s4[n], 0, 0, 0);
        }

        float val[4][4];
#pragma unroll
        for (int n = 0; n < 4; n++) {
            int ktok = t0 + n * 16 + row16;
            float ksv = ksum[((long long)b * TT + ktok) * HH + h];
#pragma unroll
            for (int r = 0; r < 4; r++) {
                int qgl = qw + quad * 4 + r;
                float d  = dbase[(long long)qgl * TT + ktok];
                float mk = mbase[(long long)qgl * TT + ktok];
                float vv = 0.125f * fmaf(d, ksv, s4[n][r]);
                val[n][r] = vv * mk + (1.0f - ceilf(mk)) * ATT_NEG;
            }
        }

        float scl[4];
#pragma unroll
        for (int r = 0; r < 4; r++) {
            float mx = fmaxf(fmaxf(val[0][r], val[1][r]), fmaxf(val[2][r], val[3][r]));
#pragma unroll
            for (int off = 1; off < 16; off <<= 1) mx = fmaxf(mx, __shfl_xor(mx, off));
            float mnew = fmaxf(m_r[r], mx);
            float sc = __expf(m_r[r] - mnew);
            float ps = 0.f;
#pragma unroll
            for (int n = 0; n < 4; n++) {
                float p = __expf(val[n][r] - mnew);
                val[n][r] = p;
                ps += p;
            }
#pragma unroll
            for (int off = 1; off < 16; off <<= 1) ps += __shfl_xor(ps, off);
            l_r[r] = l_r[r] * sc + ps;
            m_r[r] = mnew;
            scl[r] = sc;
        }
#pragma unroll
        for (int j = 0; j < 4; j++)
#pragma unroll
            for (int r = 0; r < 4; r++) o[j][r] *= scl[r];

#pragma unroll
        for (int n = 0; n < 4; n++)
#pragma unroll
            for (int r = 0; r < 4; r++)
                Pw[(quad * 4 + r) * 88 + n * 16 + row16] = (bf16_t)val[n][r];
        asm volatile("s_waitcnt lgkmcnt(0)" ::: "memory");

        bf16x8 pa0 = *(const bf16x8*)(Pw + row16 * 88 + quad * 8);
        bf16x8 pa1 = *(const bf16x8*)(Pw + row16 * 88 + 32 + quad * 8);
#pragma unroll
        for (int j = 0; j < 4; j++) {
            int row = j * 16 + row16;
            int sw = row & 7;
            bf16x8 vb0 = *(const bf16x8*)(Vs + row * 64 + ((quad ^ sw) * 8));
            bf16x8 vb1 = *(const bf16x8*)(Vs + row * 64 + (((quad + 4) ^ sw) * 8));
            o[j] = __builtin_amdgcn_mfma_f32_16x16x32_bf16(pa0, vb0, o[j], 0, 0, 0);
            o[j] = __builtin_amdgcn_mfma_f32_16x16x32_bf16(pa1, vb1, o[j], 0, 0, 0);
        }
        __syncthreads();
    }

#pragma unroll
    for (int r = 0; r < 4; r++) {
        float invl = 1.0f / l_r[r];
        int qgl = qw + quad * 4 + r;
        bf16_t* cp = ctx + (((long long)b * TT + qgl) * HH + h) * AA;
#pragma unroll
        for (int j = 0; j < 4; j++)
            cp[j * 16 + row16] = (bf16_t)(o[j][r] * invl);
    }
}

// ===========================================================================
// gemm8: 256x256 tile, BK=64, 8 waves (2M x 4N), double-buffered 128 KB LDS.
// One __syncthreads per 64-K: all 8 staging loads for tile t+1 are issued at
// the TOP of tile t (into the alternate buffer), so the barrier's vmcnt(0)
// drain is covered by 64 MFMA + 28 ds_read_b128 per wave. LDS uses the
// attn-proven XOR chunk swizzle (pre-swizzled global source, swizzled reads).
// Safety: stage targets buf[c^1] (all waves passed the previous barrier, so
// nobody still reads it); reads of buf[c] are ordered by the previous
// barrier's full drain. Same 1-barrier-per-iter discipline as the old gemm.
// ===========================================================================
#define STAGE8(kc0, cb)                                                       \
    {                                                                         \
        bf16_t* At = sm + (cb) * 16384;                                       \
        bf16_t* Bt = sm + 32768 + (cb) * 16384;                               \
        _Pragma("unroll")                                                     \
        for (int i = 0; i < 4; i++) {                                         \
            int qq = tid + i * 512;                                           \
            int r = (qq >> 3) & 127, hf = qq >> 10, ck = qq & 7;              \
            int cc = (kc0) + ((ck ^ (r & 7)) * 8);                            \
            async_load16(Ag + (long long)(m0 + hf * 128 + r) * lda + cc,      \
                         At + qq * 8);                                        \
            async_load16(Bg + (long long)(n0 + hf * 128 + r) * ldb + cc,      \
                         Bt + qq * 8);                                        \
        }                                                                     \
    }

#define LOADA8(mh)                                                            \
    _Pragma("unroll")                                                         \
    for (int mf = 0; mf < 4; mf++) {                                          \
        int ra = (mh) * 64 + mf * 16 + row16;                                 \
        _Pragma("unroll")                                                     \
        for (int ks2 = 0; ks2 < 2; ks2++)                                     \
            a8[mf][ks2] = *(const bf16x8*)(Ac + ra * 64 +                     \
                             (((ks2 * 4 + quad) ^ (ra & 7)) * 8));            \
    }

#define LOADB8(nh)                                                            \
    _Pragma("unroll")                                                         \
    for (int nf = 0; nf < 2; nf++) {                                          \
        int rb = (wn & 1) * 64 + (nh) * 32 + nf * 16 + row16;                 \
        _Pragma("unroll")                                                     \
        for (int ks2 = 0; ks2 < 2; ks2++)                                     \
            b8[nf][ks2] = *(const bf16x8*)(Bc + rb * 64 +                     \
                             (((ks2 * 4 + quad) ^ (rb & 7)) * 8));            \
    }

#define MM8(mh, nh)                                                           \
    _Pragma("unroll")                                                         \
    for (int mf = 0; mf < 4; mf++)                                            \
        _Pragma("unroll")                                                     \
        for (int nf = 0; nf < 2; nf++)                                        \
            _Pragma("unroll")                                                 \
            for (int ks2 = 0; ks2 < 2; ks2++)                                 \
                acc[(mh) * 4 + mf][(nh) * 2 + nf] =                           \
                    __builtin_amdgcn_mfma_f32_16x16x32_bf16(                  \
                        a8[mf][ks2], b8[nf][ks2],                             \
                        acc[(mh) * 4 + mf][(nh) * 2 + nf], 0, 0, 0);

template <typename TC, int ACCUM, int RELU>
__global__ __launch_bounds__(512, 2) void gemm8(
    const bf16_t* __restrict__ Ag, const bf16_t* __restrict__ Bg, TC* __restrict__ Cg,
    int K, int lda, int ldb, int ldc,
    long long sAz, long long sBz, long long sCz,
    const float* __restrict__ bias)
{
    extern __shared__ __align__(16) bf16_t sm[];
    int z = blockIdx.z;
    Ag += z * sAz; Bg += z * sBz; Cg += z * sCz;

    int tid = threadIdx.x;
    int wave = tid >> 6, lane = tid & 63;
    int wm = wave >> 2, wn = wave & 3;
    int row16 = lane & 15, quad = lane >> 4;
    int m0 = blockIdx.x * 256, n0 = blockIdx.y * 256;

    f32x4 acc[8][4] = {};

    int nt = K >> 6;
    STAGE8(0, 0);
    __syncthreads();

    int c = 0;
    for (int t = 0; t < nt; ++t, c ^= 1) {
        if (t + 1 < nt) STAGE8((t + 1) * 64, c ^ 1);
        const bf16_t* Ac = sm + c * 16384 + wm * 8192;
        const bf16_t* Bc = sm + 32768 + c * 16384 + (wn >> 1) * 8192;
        bf16x8 a8[4][2], b8[2][2];
        LOADA8(0); LOADB8(0); MM8(0, 0);
        LOADB8(1);            MM8(0, 1);
        LOADA8(1);            MM8(1, 1);
        LOADB8(0);            MM8(1, 0);
        __syncthreads();
    }

#pragma unroll
    for (int i = 0; i < 8; i++) {
#pragma unroll
        for (int j = 0; j < 4; j++) {
#pragma unroll
            for (int r = 0; r < 4; r++) {
                int m = m0 + wm * 128 + i * 16 + quad * 4 + r;
                int n = n0 + wn * 64 + j * 16 + row16;
                float vv = acc[i][j][r];
                if (bias) vv += bias[n];
                if (ACCUM) vv += (float)Cg[(long long)m * ldc + n];
                if (RELU) vv = fmaxf(vv, 0.f);
                Cg[(long long)m * ldc + n] = (TC)vv;
            }
        }
    }
}

// Split-K variant: grid.z = SPLIT. z==0 accumulates (+bias) into fp32 C
// (the residual x); z>0 writes fp32 partials P[(z-1)*NX], reduced by the
// downstream reduce_ln_kernel fused into the next LayerNorm.
template <int SPLIT>
__global__ __launch_bounds__(512, 2) void gemm8_splitk(
    const bf16_t* __restrict__ Ag, const bf16_t* __restrict__ Bg,
    float* __restrict__ Cg, float* __restrict__ Pg,
    int K, int lda, int ldb, int ldc, const float* __restrict__ bias)
{
    extern __shared__ __align__(16) bf16_t sm[];
    int z = blockIdx.z;
    int kbeg = z * (K / SPLIT);

    int tid = threadIdx.x;
    int wave = tid >> 6, lane = tid & 63;
    int wm = wave >> 2, wn = wave & 3;
    int row16 = lane & 15, quad = lane >> 4;
    int m0 = blockIdx.x * 256, n0 = blockIdx.y * 256;

    f32x4 acc[8][4] = {};

    int nt = (K / SPLIT) >> 6;
    STAGE8(kbeg, 0);
    __syncthreads();

    int c = 0;
    for (int t = 0; t < nt; ++t, c ^= 1) {
        if (t + 1 < nt) STAGE8(kbeg + (t + 1) * 64, c ^ 1);
        const bf16_t* Ac = sm + c * 16384 + wm * 8192;
        const bf16_t* Bc = sm + 32768 + c * 16384 + (wn >> 1) * 8192;
        bf16x8 a8[4][2], b8[2][2];
        LOADA8(0); LOADB8(0); MM8(0, 0);
        LOADB8(1);            MM8(0, 1);
        LOADA8(1);            MM8(1, 1);
        LOADB8(0);            MM8(1, 0);
        __syncthreads();
    }

    const long long NXc = (long long)BB * TT * DD;
#pragma unroll
    for (int i = 0; i < 8; i++) {
#pragma unroll
        for (int j = 0; j < 4; j++) {
#pragma unroll
            for (int r = 0; r < 4; r++) {
                int m = m0 + wm * 128 + i * 16 + quad * 4 + r;
                int n = n0 + wn * 64 + j * 16 + row16;
                float vv = acc[i][j][r];
                long long ci = (long long)m * ldc + n;
                if (z == 0) {
                    if (bias) vv += bias[n];
                    Cg[ci] = Cg[ci] + vv;
                } else {
                    Pg[(long long)(z - 1) * NXc + ci] = vv;
                }
            }
        }
    }
}

// ---------------------------------------------------------------------------
extern "C" void kernel_launch(void* const* d_in, const int* in_sizes, int n_in,
                              void* d_out, int out_size, void* d_ws, size_t ws_size,
                              hipStream_t stream)
{
    const int*   tokens = (const int*)d_in[0];
    const float* masks  = (const float*)d_in[1];
    const int*   ab     = (const int*)d_in[2];
    const float* embed  = (const float*)d_in[3];
    const float* Wq     = (const float*)d_in[4];
    const float* Wk     = (const float*)d_in[5];
    const float* Wv     = (const float*)d_in[6];
    const float* Wo     = (const float*)d_in[7];
    const float* be     = (const float*)d_in[8];
    const float* bs     = (const float*)d_in[9];
    const float* ln_g   = (const float*)d_in[10];
    const float* ln_b   = (const float*)d_in[11];
    const float* ff1w   = (const float*)d_in[12];
    const float* ff1b   = (const float*)d_in[13];
    const float* ff2w   = (const float*)d_in[14];
    const float* ff2b   = (const float*)d_in[15];
    const float* lng    = (const float*)d_in[16];
    const float* lnb    = (const float*)d_in[17];
    float* out = (float*)d_out;

    const long long NX = (long long)BB * TT * DD;          // 4,194,304
    // {dense, q, k, v, vT} is one contiguous region of exactly 3*NX floats:
    // doubles as the split-K partial buffer for FF2 (all dead at that point).
    float* x     = (float*)d_ws;                           // NX f32
    float* ks    = x + NX;                                 // B*T*H f32
    bf16_t* h_bf = (bf16_t*)(ks + (long long)BB * TT * HH);
    float* dense = (float*)(h_bf + NX);                    // B*T*T f32 (= NX)
    bf16_t* q    = (bf16_t*)(dense + (long long)BB * TT * TT);
    bf16_t* k    = q + NX;
    bf16_t* v    = k + NX;
    bf16_t* vT   = v + NX;
    bf16_t* wqT  = vT + NX;                                // per-layer weights
    bf16_t* wkT  = wqT + (long long)DD * DD;
    bf16_t* wvT  = wkT + (long long)DD * DD;
    bf16_t* woT  = wvT + (long long)DD * DD;
    bf16_t* ff1T = woT + (long long)DD * DD;               // [F][D]
    bf16_t* ff2T = ff1T + (long long)DD * FFD;             // [D][F]
    bf16_t* ffm  = ff2T + (long long)FFD * DD;             // [B*T, F] bf16

    float* partFF = dense;         // 3 partials (50.33 MB, dense..vT dead)

    const size_t LDS8 = 131072;    // 128 KB dynamic LDS for gemm8

    embed_pe_kernel<<<dim3(NX / 256), dim3(256), 0, stream>>>(tokens, embed, x);

    for (int l = 0; l < LNUM; l++) {
        // ln#1: for l>0 also folds in the previous layer's FF2 split-K
        // partials (x += sum P; h = LN(x)). Must precede overwrites of
        // the dense..vT region.
        if (l == 0) {
            ln_kernel<bf16_t><<<dim3(BB * TT), dim3(256), 0, stream>>>(
                x, h_bf, ln_g + (l * 2 + 0) * DD, ln_b + (l * 2 + 0) * DD);
        } else {
            reduce_ln_kernel<bf16_t, 3><<<dim3(BB * TT), dim3(256), 0, stream>>>(
                x, partFF, h_bf, ln_g + (l * 2 + 0) * DD, ln_b + (l * 2 + 0) * DD);
        }

        Ptr4 p4;
        p4.p[0] = Wq + (long long)l * DD * HH * AA;
        p4.p[1] = Wk + (long long)l * DD * HH * AA;
        p4.p[2] = Wv + (long long)l * DD * HH * AA;
        p4.p[3] = Wo + (long long)l * HH * AA * DD;
        wconv4_kernel<<<dim3(8, 8, 4), dim3(256), 0, stream>>>(p4, wqT);
        wconv_kernel<<<dim3(FFD / 64, DD / 64, 1), dim3(256), 0, stream>>>(
            ff1w + (long long)l * DD * FFD, ff1T, DD, FFD);
        wconv_kernel<<<dim3(DD / 64, FFD / 64, 1), dim3(256), 0, stream>>>(
            ff2w + (long long)l * FFD * DD, ff2T, FFD, DD);

        const float* ff1b_l = ff1b + (long long)l * FFD;
        const float* ff2b_l = ff2b + (long long)l * DD;

        // q/k/v in ONE launch: 192 blocks of 8 waves
        gemm8<bf16_t, 0, 0><<<dim3(32, 2, 3), dim3(512), LDS8, stream>>>(
            h_bf, wqT, q, 512, 512, 512, 512,
            0LL, (long long)DD * DD, NX, nullptr);

        vtrans_kernel<<<dim3(8, BB * HH), dim3(256), 0, stream>>>(v, vT);
        ksum_kernel<<<dim3(BB * TT * HH / 256), dim3(256), 0, stream>>>(k, ks);

        hipMemsetAsync(dense, 0, sizeof(float) * (size_t)BB * TT * TT, stream);
        bias_scatter_kernel<<<dim3((EE + 255) / 256), dim3(256), 0, stream>>>(
            ab, be + (long long)l * BIASDIM * AA, bs + (long long)l * AA, dense);

        fused_attn_kernel<<<dim3(TT / 64, BB * HH), dim3(256), 0, stream>>>(
            q, k, vT, dense, ks, masks, h_bf);

        // x += ctx @ Wo  — direct fp32 accumulate, 64 blocks (no split)
        gemm8<float, 1, 0><<<dim3(32, 2, 1), dim3(512), LDS8, stream>>>(
            h_bf, woT, x, 512, 512, 512, 512, 0LL, 0LL, 0LL, nullptr);

        ln_kernel<bf16_t><<<dim3(BB * TT), dim3(256), 0, stream>>>(
            x, h_bf, ln_g + (l * 2 + 1) * DD, ln_b + (l * 2 + 1) * DD);

        // ffm = relu(h @ W1 + b1): 256 blocks = exactly 1/CU
        gemm8<bf16_t, 0, 1><<<dim3(32, 8, 1), dim3(512), LDS8, stream>>>(
            h_bf, ff1T, ffm, 512, 512, 512, 2048, 0LL, 0LL, 0LL, ff1b_l);

        // x += ffm @ W2 + b2 — split-K x4 (256 blocks): z0 accums into x,
        // z1..z3 write partials into dense..vT (all dead here).
        gemm8_splitk<4><<<dim3(32, 2, 4), dim3(512), LDS8, stream>>>(
            ffm, ff2T, x, partFF, 2048, 2048, 2048, 512, ff2b_l);
    }

    // final LN fused with the last layer's FF2 partial reduce
    reduce_ln_kernel<float, 3><<<dim3(BB * TT), dim3(256), 0, stream>>>(
        x, partFF, out, lng, lnb);
}

// Round 4
// 1531.670 us; speedup vs baseline: 1.2172x; 1.2172x over previous
//
#include <hip/hip_runtime.h>
#include <hip/hip_bf16.h>

#define LNUM 6
#define BB 16
#define TT 512
#define DD 512
#define HH 8
#define AA 64
#define FFD 2048
#define EE 200000
#define BIASDIM 4
#define ATT_NEG (-3.402823466e38f)

typedef __bf16 bf16_t;
typedef __attribute__((ext_vector_type(8))) __bf16 bf16x8;
typedef __attribute__((ext_vector_type(4))) float f32x4;

typedef __attribute__((address_space(3))) void lds_void;
typedef const __attribute__((address_space(1))) void glb_void;

__device__ __forceinline__ void async_load16(const bf16_t* g, bf16_t* l) {
    __builtin_amdgcn_global_load_lds((glb_void*)g, (lds_void*)l, 16, 0, 0);
}

// ---------------------------------------------------------------------------
// Embedding + positional encoding (fp32 out)
// ---------------------------------------------------------------------------
__global__ __launch_bounds__(256) void embed_pe_kernel(
    const int* __restrict__ tokens, const float* __restrict__ embed,
    float* __restrict__ x)
{
    int idx = blockIdx.x * 256 + threadIdx.x;
    int d  = idx & (DD - 1);
    int bt = idx >> 9;
    int t  = bt & (TT - 1);
    int tok = tokens[bt];
    float e = embed[(long long)tok * DD + d] * 22.62741699796952f; // sqrt(512)
    float p = (float)(2 * (d >> 1)) * (1.0f / (float)DD);
    float denom = exp2f(p * 13.287712379549449f);  // 10000^p
    float angle = (float)t / denom;
    float pe = (d & 1) ? cosf(angle) : sinf(angle);
    x[idx] = e + pe;
}

// ---------------------------------------------------------------------------
// LayerNorm over D=512, fp32 in, TO out
// ---------------------------------------------------------------------------
template <typename TO>
__global__ __launch_bounds__(256) void ln_kernel(
    const float* __restrict__ x, TO* __restrict__ y,
    const float* __restrict__ g, const float* __restrict__ b)
{
    long long row = blockIdx.x;
    const float* xr = x + row * DD;
    int tid = threadIdx.x;
    float v0 = xr[tid], v1 = xr[tid + 256];
    float s = v0 + v1, sq = v0 * v0 + v1 * v1;
#pragma unroll
    for (int o = 32; o > 0; o >>= 1) {
        s  += __shfl_down(s, o);
        sq += __shfl_down(sq, o);
    }
    __shared__ float ss[4], sq4[4];
    if ((tid & 63) == 0) { ss[tid >> 6] = s; sq4[tid >> 6] = sq; }
    __syncthreads();
    float st  = ss[0] + ss[1] + ss[2] + ss[3];
    float sqt = sq4[0] + sq4[1] + sq4[2] + sq4[3];
    float mean = st * (1.0f / DD);
    float var  = sqt * (1.0f / DD) - mean * mean;
    float inv  = rsqrtf(var + 1e-3f);
    y[row * DD + tid]       = (TO)((v0 - mean) * inv * g[tid]       + b[tid]);
    y[row * DD + tid + 256] = (TO)((v1 - mean) * inv * g[tid + 256] + b[tid + 256]);
}

// ---------------------------------------------------------------------------
// Fused split-K partial reduce + residual update + LayerNorm.
// v = x + sum_s P[s];  x = v (residual write-back);  y = LN(v)
// ---------------------------------------------------------------------------
template <typename TO, int S>
__global__ __launch_bounds__(256) void reduce_ln_kernel(
    float* __restrict__ x, const float* __restrict__ P,
    TO* __restrict__ y, const float* __restrict__ g, const float* __restrict__ b)
{
    const long long NXc = (long long)BB * TT * DD;
    long long row = blockIdx.x;
    int tid = threadIdx.x;
    long long i0 = row * DD + tid;
    float v0 = x[i0], v1 = x[i0 + 256];
#pragma unroll
    for (int s = 0; s < S; s++) {
        v0 += P[(long long)s * NXc + i0];
        v1 += P[(long long)s * NXc + i0 + 256];
    }
    x[i0] = v0; x[i0 + 256] = v1;
    float s2 = v0 + v1, sq = v0 * v0 + v1 * v1;
#pragma unroll
    for (int o = 32; o > 0; o >>= 1) {
        s2 += __shfl_down(s2, o);
        sq += __shfl_down(sq, o);
    }
    __shared__ float ss[4], sq4[4];
    if ((tid & 63) == 0) { ss[tid >> 6] = s2; sq4[tid >> 6] = sq; }
    __syncthreads();
    float st  = ss[0] + ss[1] + ss[2] + ss[3];
    float sqt = sq4[0] + sq4[1] + sq4[2] + sq4[3];
    float mean = st * (1.0f / DD);
    float var  = sqt * (1.0f / DD) - mean * mean;
    float inv  = rsqrtf(var + 1e-3f);
    y[i0]       = (TO)((v0 - mean) * inv * g[tid]       + b[tid]);
    y[i0 + 256] = (TO)((v1 - mean) * inv * g[tid + 256] + b[tid + 256]);
}

// ---------------------------------------------------------------------------
// ksum[b,t,h] = sum_a k_bf[b,t,h,a]
// ---------------------------------------------------------------------------
__global__ __launch_bounds__(256) void ksum_kernel(
    const bf16_t* __restrict__ k, float* __restrict__ ks)
{
    int idx = blockIdx.x * 256 + threadIdx.x;
    long long base = (long long)idx * AA;
    float s = 0.f;
#pragma unroll
    for (int a = 0; a < AA; a++) s += (float)k[base + a];
    ks[idx] = s;
}

// ---------------------------------------------------------------------------
// Edge-bias scatter
// ---------------------------------------------------------------------------
__global__ __launch_bounds__(256) void bias_scatter_kernel(
    const int* __restrict__ ab, const float* __restrict__ be,
    const float* __restrict__ bs, float* __restrict__ dense)
{
    __shared__ float ev[BIASDIM];
    int tid = threadIdx.x;
    if (tid < BIASDIM) {
        float s = 0.f;
        for (int a = 0; a < AA; a++) s += be[tid * AA + a] * bs[a];
        ev[tid] = s;
    }
    __syncthreads();
    int e = blockIdx.x * 256 + tid;
    if (e < EE) {
        int ty = ab[e * 4 + 0];
        int b  = ab[e * 4 + 1];
        int q  = ab[e * 4 + 2];
        int kk = ab[e * 4 + 3];
        unsafeAtomicAdd(&dense[((long long)b * TT + q) * TT + kk], ev[ty]);
    }
}

// ---------------------------------------------------------------------------
// Weight convert+transpose: in fp32 [R,Cc] -> out bf16 [Cc,R]. 64x64 tiles.
// ---------------------------------------------------------------------------
__global__ __launch_bounds__(256) void wconv_kernel(
    const float* __restrict__ in, bf16_t* __restrict__ out, int R, int Cc)
{
    __shared__ bf16_t tile[64][65];
    int c0 = blockIdx.x * 64, r0 = blockIdx.y * 64;
    int tid = threadIdx.x;
#pragma unroll
    for (int i = 0; i < 16; i++) {
        int idx = tid + i * 256; int r = idx >> 6, c = idx & 63;
        tile[c][r] = (bf16_t)in[(long long)(r0 + r) * Cc + c0 + c];
    }
    __syncthreads();
#pragma unroll
    for (int i = 0; i < 16; i++) {
        int idx = tid + i * 256; int rr = idx >> 6, cc = idx & 63;
        out[(long long)(c0 + rr) * R + r0 + cc] = tile[rr][cc];
    }
}

struct Ptr4 { const float* p[4]; };

__global__ __launch_bounds__(256) void wconv4_kernel(Ptr4 srcs, bf16_t* __restrict__ out)
{
    __shared__ bf16_t tile[64][65];
    int z = blockIdx.z;
    const float* in = srcs.p[z];
    bf16_t* o = out + (long long)z * DD * DD;
    int c0 = blockIdx.x * 64, r0 = blockIdx.y * 64;
    int tid = threadIdx.x;
#pragma unroll
    for (int i = 0; i < 16; i++) {
        int idx = tid + i * 256; int r = idx >> 6, c = idx & 63;
        tile[c][r] = (bf16_t)in[(long long)(r0 + r) * DD + c0 + c];
    }
    __syncthreads();
#pragma unroll
    for (int i = 0; i < 16; i++) {
        int idx = tid + i * 256; int rr = idx >> 6, cc = idx & 63;
        o[(long long)(c0 + rr) * DD + r0 + cc] = tile[rr][cc];
    }
}

// ---------------------------------------------------------------------------
// v [B,T,H,A] bf16 -> vT [B,H,A,T] bf16
// ---------------------------------------------------------------------------
__global__ __launch_bounds__(256) void vtrans_kernel(
    const bf16_t* __restrict__ v, bf16_t* __restrict__ vT)
{
    __shared__ bf16_t tile[64][65];
    int bh = blockIdx.y; int b = bh >> 3, h = bh & 7;
    int t0 = blockIdx.x * 64;
    int tid = threadIdx.x;
#pragma unroll
    for (int i = 0; i < 16; i++) {
        int idx = tid + i * 256; int r = idx >> 6, c = idx & 63;  // r: t, c: a
        tile[c][r] = v[((long long)(b * TT + t0 + r) * HH + h) * AA + c];
    }
    __syncthreads();
#pragma unroll
    for (int i = 0; i < 16; i++) {
        int idx = tid + i * 256; int a = idx >> 6, t2 = idx & 63;
        vT[(((long long)b * HH + h) * AA + a) * TT + t0 + t2] = tile[a][t2];
    }
}

// ---------------------------------------------------------------------------
// Fused attention. Unchanged.
// ---------------------------------------------------------------------------
__global__ __launch_bounds__(256) void fused_attn_kernel(
    const bf16_t* __restrict__ qg, const bf16_t* __restrict__ kg,
    const bf16_t* __restrict__ vT, const float* __restrict__ dense,
    const float* __restrict__ ksum, const float* __restrict__ masks,
    bf16_t* __restrict__ ctx)
{
    __shared__ __align__(16) bf16_t Ks[64 * 64];
    __shared__ __align__(16) bf16_t Vs[64 * 64];
    __shared__ __align__(16) bf16_t Plds[4 * 16 * 88];

    int tid = threadIdx.x;
    int wave = tid >> 6, lane = tid & 63;
    int row16 = lane & 15, quad = lane >> 4;
    int bh = blockIdx.y; int b = bh >> 3, h = bh & 7;
    int qw = blockIdx.x * 64 + wave * 16;

    bf16x8 qf[2];
    {
        const bf16_t* qp = qg + (((long long)b * TT + qw + row16) * HH + h) * AA + quad * 8;
        qf[0] = *(const bf16x8*)(qp);
        qf[1] = *(const bf16x8*)(qp + 32);
    }

    f32x4 o[4] = {};
    float m_r[4], l_r[4];
#pragma unroll
    for (int r = 0; r < 4; r++) { m_r[r] = -3.0e38f; l_r[r] = 0.f; }

    bf16_t* Pw = Plds + wave * 16 * 88;
    const float* dbase = dense + (long long)b * TT * TT;
    const float* mbase = masks + (long long)b * TT * TT;

    for (int kt = 0; kt < 8; kt++) {
        int t0 = kt * 64;
#pragma unroll
        for (int p = tid; p < 512; p += 256) {
            int r = p >> 3, s = p & 7, c = s ^ (r & 7);
            async_load16(kg + (((long long)b * TT + t0 + r) * HH + h) * AA + c * 8,
                         Ks + p * 8);
        }
#pragma unroll
        for (int p = tid; p < 512; p += 256) {
            int r = p >> 3, s = p & 7, c = s ^ (r & 7);
            async_load16(vT + ((long long)bh * AA + r) * TT + t0 + c * 8,
                         Vs + p * 8);
        }
        __syncthreads();

        f32x4 s4[4] = {};
#pragma unroll
        for (int n = 0; n < 4; n++) {
            int row = n * 16 + row16;
            int sw = row & 7;
            bf16x8 kf0 = *(const bf16x8*)(Ks + row * 64 + ((quad ^ sw) * 8));
            bf16x8 kf1 = *(const bf16x8*)(Ks + row * 64 + (((quad + 4) ^ sw) * 8));
            s4[n] = __builtin_amdgcn_mfma_f32_16x16x32_bf16(qf[0], kf0, s4[n], 0, 0, 0);
            s4[n] = __builtin_amdgcn_mfma_f32_16x16x32_bf16(qf[1], kf1, s4[n], 0, 0, 0);
        }

        float val[4][4];
#pragma unroll
        for (int n = 0; n < 4; n++) {
            int ktok = t0 + n * 16 + row16;
            float ksv = ksum[((long long)b * TT + ktok) * HH + h];
#pragma unroll
            for (int r = 0; r < 4; r++) {
                int qgl = qw + quad * 4 + r;
                float d  = dbase[(long long)qgl * TT + ktok];
                float mk = mbase[(long long)qgl * TT + ktok];
                float vv = 0.125f * fmaf(d, ksv, s4[n][r]);
                val[n][r] = vv * mk + (1.0f - ceilf(mk)) * ATT_NEG;
            }
        }

        float scl[4];
#pragma unroll
        for (int r = 0; r < 4; r++) {
            float mx = fmaxf(fmaxf(val[0][r], val[1][r]), fmaxf(val[2][r], val[3][r]));
#pragma unroll
            for (int off = 1; off < 16; off <<= 1) mx = fmaxf(mx, __shfl_xor(mx, off));
            float mnew = fmaxf(m_r[r], mx);
            float sc = __expf(m_r[r] - mnew);
            float ps = 0.f;
#pragma unroll
            for (int n = 0; n < 4; n++) {
                float p = __expf(val[n][r] - mnew);
                val[n][r] = p;
                ps += p;
            }
#pragma unroll
            for (int off = 1; off < 16; off <<= 1) ps += __shfl_xor(ps, off);
            l_r[r] = l_r[r] * sc + ps;
            m_r[r] = mnew;
            scl[r] = sc;
        }
#pragma unroll
        for (int j = 0; j < 4; j++)
#pragma unroll
            for (int r = 0; r < 4; r++) o[j][r] *= scl[r];

#pragma unroll
        for (int n = 0; n < 4; n++)
#pragma unroll
            for (int r = 0; r < 4; r++)
                Pw[(quad * 4 + r) * 88 + n * 16 + row16] = (bf16_t)val[n][r];
        asm volatile("s_waitcnt lgkmcnt(0)" ::: "memory");

        bf16x8 pa0 = *(const bf16x8*)(Pw + row16 * 88 + quad * 8);
        bf16x8 pa1 = *(const bf16x8*)(Pw + row16 * 88 + 32 + quad * 8);
#pragma unroll
        for (int j = 0; j < 4; j++) {
            int row = j * 16 + row16;
            int sw = row & 7;
            bf16x8 vb0 = *(const bf16x8*)(Vs + row * 64 + ((quad ^ sw) * 8));
            bf16x8 vb1 = *(const bf16x8*)(Vs + row * 64 + (((quad + 4) ^ sw) * 8));
            o[j] = __builtin_amdgcn_mfma_f32_16x16x32_bf16(pa0, vb0, o[j], 0, 0, 0);
            o[j] = __builtin_amdgcn_mfma_f32_16x16x32_bf16(pa1, vb1, o[j], 0, 0, 0);
        }
        __syncthreads();
    }

#pragma unroll
    for (int r = 0; r < 4; r++) {
        float invl = 1.0f / l_r[r];
        int qgl = qw + quad * 4 + r;
        bf16_t* cp = ctx + (((long long)b * TT + qgl) * HH + h) * AA;
#pragma unroll
        for (int j = 0; j < 4; j++)
            cp[j * 16 + row16] = (bf16_t)(o[j][r] * invl);
    }
}

// ===========================================================================
// gemm_pipe: 128x128 tile, BK=64, 4 waves, 64 KB double-buffered LDS,
// COUNTED-vmcnt pipeline (no full drain in the main loop):
//   iter t (slot s=t&1):
//     STAGE(tile t+1 -> slot s^1)       // 8 global_load_lds, stay in flight
//     s_waitcnt vmcnt(8)                // my tile-t loads retired
//     s_barrier                         // everyone's tile-t loads retired
//     ds_read frags from slot s (16 x ds_read_b128, XOR-swizzled)
//     s_waitcnt lgkmcnt(0)
//     s_barrier                         // all reads of slot s retired ->
//                                       //   next iter may overwrite it
//     setprio(1); 32 MFMA; setprio(0)   // MFMA pipe overlaps next iter's
//                                       //   stage issue + vmcnt wait
// Hazards: WAR on slot s protected by barrier #2 (stage of tile t+2 sits
// after it in program order for every wave); RAW on slot s^1 protected by
// per-wave vmcnt(8) + barrier #1 (in-order VMEM retirement). sched_barrier(0)
// after each asm wait (rule 18). 2 blocks/CU (64 KB LDS) restores TLP.
// ===========================================================================
#define PSTAGE(kc0, slot)                                                     \
    {                                                                         \
        bf16_t* At = sm + (slot) * 16384;                                     \
        bf16_t* Bt = At + 8192;                                               \
        _Pragma("unroll")                                                     \
        for (int i = 0; i < 4; i++) {                                         \
            int qq = tid + i * 256;                                           \
            int r = qq >> 3, ck = qq & 7;                                     \
            int cc = (kc0) + ((ck ^ (r & 7)) * 8);                            \
            async_load16(Ag + (long long)(m0 + r) * lda + cc, At + qq * 8);   \
            async_load16(Bg + (long long)(n0 + r) * ldb + cc, Bt + qq * 8);   \
        }                                                                     \
    }

#define PLOAD()                                                               \
    _Pragma("unroll")                                                         \
    for (int mf = 0; mf < 4; mf++) {                                          \
        int ra = wm * 64 + mf * 16 + row16;                                   \
        _Pragma("unroll")                                                     \
        for (int ks2 = 0; ks2 < 2; ks2++)                                     \
            a8[mf][ks2] = *(const bf16x8*)(Ac + ra * 64 +                     \
                              (((ks2 * 4 + quad) ^ (ra & 7)) * 8));           \
    }                                                                         \
    _Pragma("unroll")                                                         \
    for (int nf = 0; nf < 4; nf++) {                                          \
        int rb = wn * 64 + nf * 16 + row16;                                   \
        _Pragma("unroll")                                                     \
        for (int ks2 = 0; ks2 < 2; ks2++)                                     \
            b8[nf][ks2] = *(const bf16x8*)(Bc + rb * 64 +                     \
                              (((ks2 * 4 + quad) ^ (rb & 7)) * 8));           \
    }

#define PMM()                                                                 \
    _Pragma("unroll")                                                         \
    for (int mf = 0; mf < 4; mf++)                                            \
        _Pragma("unroll")                                                     \
        for (int nf = 0; nf < 4; nf++)                                        \
            _Pragma("unroll")                                                 \
            for (int ks2 = 0; ks2 < 2; ks2++)                                 \
                acc[mf][nf] = __builtin_amdgcn_mfma_f32_16x16x32_bf16(        \
                    a8[mf][ks2], b8[nf][ks2], acc[mf][nf], 0, 0, 0);

#define PIPE_BODY(KBEG, NT)                                                   \
    PSTAGE((KBEG), 0);                                                        \
    int c = 0;                                                                \
    for (int t = 0; t < (NT); ++t, c ^= 1) {                                  \
        if (t + 1 < (NT)) {                                                   \
            PSTAGE((KBEG) + (t + 1) * 64, c ^ 1);                             \
            asm volatile("s_waitcnt vmcnt(8)" ::: "memory");                  \
        } else {                                                              \
            asm volatile("s_waitcnt vmcnt(0)" ::: "memory");                  \
        }                                                                     \
        __builtin_amdgcn_sched_barrier(0);                                    \
        __builtin_amdgcn_s_barrier();                                         \
        __builtin_amdgcn_sched_barrier(0);                                    \
        const bf16_t* Ac = sm + c * 16384;                                    \
        const bf16_t* Bc = Ac + 8192;                                         \
        bf16x8 a8[4][2], b8[4][2];                                            \
        PLOAD();                                                              \
        asm volatile("s_waitcnt lgkmcnt(0)" ::: "memory");                    \
        __builtin_amdgcn_sched_barrier(0);                                    \
        __builtin_amdgcn_s_barrier();                                         \
        __builtin_amdgcn_sched_barrier(0);                                    \
        __builtin_amdgcn_s_setprio(1);                                        \
        PMM();                                                                \
        __builtin_amdgcn_s_setprio(0);                                        \
    }

template <typename TC, int ACCUM, int RELU>
__global__ __launch_bounds__(256, 2) void gemm_pipe(
    const bf16_t* __restrict__ Ag, const bf16_t* __restrict__ Bg, TC* __restrict__ Cg,
    int K, int lda, int ldb, int ldc,
    long long sAz, long long sBz, long long sCz,
    const float* __restrict__ bias)
{
    extern __shared__ __align__(16) bf16_t sm[];
    int z = blockIdx.z;
    Ag += z * sAz; Bg += z * sBz; Cg += z * sCz;

    int tid = threadIdx.x;
    int wave = tid >> 6, lane = tid & 63;
    int wm = wave >> 1, wn = wave & 1;
    int row16 = lane & 15, quad = lane >> 4;
    int m0 = blockIdx.x * 128, n0 = blockIdx.y * 128;

    f32x4 acc[4][4] = {};
    int nt = K >> 6;
    PIPE_BODY(0, nt);

#pragma unroll
    for (int mf = 0; mf < 4; mf++) {
#pragma unroll
        for (int nf = 0; nf < 4; nf++) {
#pragma unroll
            for (int r = 0; r < 4; r++) {
                int m = m0 + wm * 64 + mf * 16 + quad * 4 + r;
                int n = n0 + wn * 64 + nf * 16 + row16;
                float vv = acc[mf][nf][r];
                if (bias) vv += bias[n];
                if (ACCUM) vv += (float)Cg[(long long)m * ldc + n];
                if (RELU) vv = fmaxf(vv, 0.f);
                Cg[(long long)m * ldc + n] = (TC)vv;
            }
        }
    }
}

// Split-K variant: grid.z = SPLIT. z==0 accumulates (+bias) into fp32 C
// (the residual x); z>0 writes fp32 partials P[(z-1)*NX], reduced by the
// downstream reduce_ln_kernel fused into the next LayerNorm.
template <int SPLIT>
__global__ __launch_bounds__(256, 2) void gemm_pipe_splitk(
    const bf16_t* __restrict__ Ag, const bf16_t* __restrict__ Bg,
    float* __restrict__ Cg, float* __restrict__ Pg,
    int K, int lda, int ldb, int ldc, const float* __restrict__ bias)
{
    extern __shared__ __align__(16) bf16_t sm[];
    int z = blockIdx.z;
    int kbeg = z * (K / SPLIT);

    int tid = threadIdx.x;
    int wave = tid >> 6, lane = tid & 63;
    int wm = wave >> 1, wn = wave & 1;
    int row16 = lane & 15, quad = lane >> 4;
    int m0 = blockIdx.x * 128, n0 = blockIdx.y * 128;

    f32x4 acc[4][4] = {};
    int nt = (K / SPLIT) >> 6;
    PIPE_BODY(kbeg, nt);

    const long long NXc = (long long)BB * TT * DD;
#pragma unroll
    for (int mf = 0; mf < 4; mf++) {
#pragma unroll
        for (int nf = 0; nf < 4; nf++) {
#pragma unroll
            for (int r = 0; r < 4; r++) {
                int m = m0 + wm * 64 + mf * 16 + quad * 4 + r;
                int n = n0 + wn * 64 + nf * 16 + row16;
                float vv = acc[mf][nf][r];
                long long ci = (long long)m * ldc + n;
                if (z == 0) {
                    if (bias) vv += bias[n];
                    Cg[ci] = Cg[ci] + vv;
                } else {
                    Pg[(long long)(z - 1) * NXc + ci] = vv;
                }
            }
        }
    }
}

// ---------------------------------------------------------------------------
extern "C" void kernel_launch(void* const* d_in, const int* in_sizes, int n_in,
                              void* d_out, int out_size, void* d_ws, size_t ws_size,
                              hipStream_t stream)
{
    const int*   tokens = (const int*)d_in[0];
    const float* masks  = (const float*)d_in[1];
    const int*   ab     = (const int*)d_in[2];
    const float* embed  = (const float*)d_in[3];
    const float* Wq     = (const float*)d_in[4];
    const float* Wk     = (const float*)d_in[5];
    const float* Wv     = (const float*)d_in[6];
    const float* Wo     = (const float*)d_in[7];
    const float* be     = (const float*)d_in[8];
    const float* bs     = (const float*)d_in[9];
    const float* ln_g   = (const float*)d_in[10];
    const float* ln_b   = (const float*)d_in[11];
    const float* ff1w   = (const float*)d_in[12];
    const float* ff1b   = (const float*)d_in[13];
    const float* ff2w   = (const float*)d_in[14];
    const float* ff2b   = (const float*)d_in[15];
    const float* lng    = (const float*)d_in[16];
    const float* lnb    = (const float*)d_in[17];
    float* out = (float*)d_out;

    const long long NX = (long long)BB * TT * DD;          // 4,194,304
    // {dense, q, k, v, vT} is one contiguous region of exactly 3*NX floats:
    // doubles as the split-K partial buffer for FF2 (all dead at that point).
    float* x     = (float*)d_ws;                           // NX f32
    float* ks    = x + NX;                                 // B*T*H f32
    bf16_t* h_bf = (bf16_t*)(ks + (long long)BB * TT * HH);
    float* dense = (float*)(h_bf + NX);                    // B*T*T f32 (= NX)
    bf16_t* q    = (bf16_t*)(dense + (long long)BB * TT * TT);
    bf16_t* k    = q + NX;
    bf16_t* v    = k + NX;
    bf16_t* vT   = v + NX;
    bf16_t* wqT  = vT + NX;                                // per-layer weights
    bf16_t* wkT  = wqT + (long long)DD * DD;
    bf16_t* wvT  = wkT + (long long)DD * DD;
    bf16_t* woT  = wvT + (long long)DD * DD;
    bf16_t* ff1T = woT + (long long)DD * DD;               // [F][D]
    bf16_t* ff2T = ff1T + (long long)DD * FFD;             // [D][F]
    bf16_t* ffm  = ff2T + (long long)FFD * DD;             // [B*T, F] bf16

    float* partCtx = dense;        // 1 partial  (dense dead post-attn)
    float* partFF  = dense;        // 3 partials (dense..vT dead)

    const size_t LDSP = 65536;     // 64 KB dynamic LDS for gemm_pipe

    embed_pe_kernel<<<dim3(NX / 256), dim3(256), 0, stream>>>(tokens, embed, x);

    for (int l = 0; l < LNUM; l++) {
        // ln#1: for l>0 also folds in the previous layer's FF2 split-K
        // partials (x += sum P; h = LN(x)). Must precede overwrites of
        // the dense..vT region.
        if (l == 0) {
            ln_kernel<bf16_t><<<dim3(BB * TT), dim3(256), 0, stream>>>(
                x, h_bf, ln_g + (l * 2 + 0) * DD, ln_b + (l * 2 + 0) * DD);
        } else {
            reduce_ln_kernel<bf16_t, 3><<<dim3(BB * TT), dim3(256), 0, stream>>>(
                x, partFF, h_bf, ln_g + (l * 2 + 0) * DD, ln_b + (l * 2 + 0) * DD);
        }

        Ptr4 p4;
        p4.p[0] = Wq + (long long)l * DD * HH * AA;
        p4.p[1] = Wk + (long long)l * DD * HH * AA;
        p4.p[2] = Wv + (long long)l * DD * HH * AA;
        p4.p[3] = Wo + (long long)l * HH * AA * DD;
        wconv4_kernel<<<dim3(8, 8, 4), dim3(256), 0, stream>>>(p4, wqT);
        wconv_kernel<<<dim3(FFD / 64, DD / 64, 1), dim3(256), 0, stream>>>(
            ff1w + (long long)l * DD * FFD, ff1T, DD, FFD);
        wconv_kernel<<<dim3(DD / 64, FFD / 64, 1), dim3(256), 0, stream>>>(
            ff2w + (long long)l * FFD * DD, ff2T, FFD, DD);

        const float* ff1b_l = ff1b + (long long)l * FFD;
        const float* ff2b_l = ff2b + (long long)l * DD;

        // q/k/v in ONE launch: 768 blocks, 2 blocks/CU residency
        gemm_pipe<bf16_t, 0, 0><<<dim3(64, 4, 3), dim3(256), LDSP, stream>>>(
            h_bf, wqT, q, 512, 512, 512, 512,
            0LL, (long long)DD * DD, NX, nullptr);

        vtrans_kernel<<<dim3(8, BB * HH), dim3(256), 0, stream>>>(v, vT);
        ksum_kernel<<<dim3(BB * TT * HH / 256), dim3(256), 0, stream>>>(k, ks);

        hipMemsetAsync(dense, 0, sizeof(float) * (size_t)BB * TT * TT, stream);
        bias_scatter_kernel<<<dim3((EE + 255) / 256), dim3(256), 0, stream>>>(
            ab, be + (long long)l * BIASDIM * AA, bs + (long long)l * AA, dense);

        fused_attn_kernel<<<dim3(TT / 64, BB * HH), dim3(256), 0, stream>>>(
            q, k, vT, dense, ks, masks, h_bf);

        // x += ctx @ Wo  — split-K x2 (512 blocks): z0 accums into x,
        // z1 writes a partial into the (now dead) dense region.
        gemm_pipe_splitk<2><<<dim3(64, 4, 2), dim3(256), LDSP, stream>>>(
            h_bf, woT, x, partCtx, 512, 512, 512, 512, nullptr);

        // ln#2 fused with the ctx@Wo partial reduce
        reduce_ln_kernel<bf16_t, 1><<<dim3(BB * TT), dim3(256), 0, stream>>>(
            x, partCtx, h_bf, ln_g + (l * 2 + 1) * DD, ln_b + (l * 2 + 1) * DD);

        // ffm = relu(h @ W1 + b1): 1024 blocks
        gemm_pipe<bf16_t, 0, 1><<<dim3(64, 16, 1), dim3(256), LDSP, stream>>>(
            h_bf, ff1T, ffm, 512, 512, 512, 2048, 0LL, 0LL, 0LL, ff1b_l);

        // x += ffm @ W2 + b2 — split-K x4 (1024 blocks): z0 accums into x,
        // z1..z3 write partials into dense..vT (all dead here).
        gemm_pipe_splitk<4><<<dim3(64, 4, 4), dim3(256), LDSP, stream>>>(
            ffm, ff2T, x, partFF, 2048, 2048, 2048, 512, ff2b_l);
    }

    // final LN fused with the last layer's FF2 partial reduce
    reduce_ln_kernel<float, 3><<<dim3(BB * TT), dim3(256), 0, stream>>>(
        x, partFF, out, lng, lnb);
}